// Round 10
// baseline (6590.662 us; speedup 1.0000x reference)
//
#include <hip/hip_runtime.h>

// Autoregressive LSTM on MI355X (gfx950).
// B=256, T=256, D=256, H=1024, O=256.
// Persistent 256-block kernel; weights LDS-resident; fence-free steady state
// (sc1 write-through stores + 16-slot ring + acquire fence every 16 steps);
// two independent 128-block groups.
// Round 10: wave specialization. Waves 0-3 = R7 GEMM core (xGEMM/hGEMM/yGEMM/
// epilogue, M=32/wave). Waves 4-7 = phaseB (y projection), running in
// parallel with hGEMM so y's barrier propagation hides under it. No
// __syncthreads in the steady loop: per-wave global-flag polls + LDS counter
// syncs (monotonic epochs) + explicit vmcnt(0) before flag publication.

typedef _Float16 f16x8 __attribute__((ext_vector_type(8)));
typedef _Float16 f16x4 __attribute__((ext_vector_type(4)));
typedef float f32x4 __attribute__((ext_vector_type(4)));

#define TSTEPS 256
#define HID 1024
#define OUTD 256
#define KF 1536            // D + H + O (WfullT K)
#define KA 1280            // ring row: h[0..1024) | y[1024..1280)
#define NBLK 256
#define RSLOTS 16
#define SLOTE (256 * KA)   // elements per ring slot

// workspace layout (bytes)
#define RING_OFF   0ull                       // fp16 16*256*1280 = 10,485,760 (aliases WfullT)
#define WFULLT_OFF 0ull                       // fp16 [4096][1536] = 12,582,912 (init-only)
#define WDT_OFF    12582912ull                // fp16 [256][1024]  = 524,288
#define XH_OFF     13107200ull                // fp16 [256][256][256] = 33,554,432
#define CNT_OFF    46661632ull                // sub-counters (1KB region)
#define WS_NEEDED  46663680ull

// counter layout (ints): hcnt grp0 @0, grp1 @64; ycnt grp0 @128, grp1 @192
#define HCNT(g) ((g) * 64)
#define YCNT(g) (128 + (g) * 64)

// LDS layout (bytes)
#define LDS_SLAB 98304                        // 32 vcols * 192 kblks * 16B
#define LDS_WDT  32768                        // 16 cols * 128 kblks * 16B
#define LDS_ZBUF 16896                        // [128][33] f32
#define LDS_RED  4096                         // [4][256] f32 (phaseB partials)
#define LDS_YS   512                          // [256] u16
#define LDS_SYNC 64                           // sync counters
#define LDS_TOTAL (LDS_SLAB + LDS_WDT + LDS_ZBUF + LDS_RED + LDS_YS + LDS_SYNC)

#define AGENT __HIP_MEMORY_SCOPE_AGENT
#define WG    __HIP_MEMORY_SCOPE_WORKGROUP

// sync counter indices
#define SY_ZS 0   // zbuf written (waves 0-3)
#define SY_HS 1   // h stored     (waves 0-3)
#define SY_P1 2   // red written  (waves 4-7)
#define SY_P2 3   // ys written   (waves 4-7)
#define SY_YA 4   // y stored     (waves 4-7)

__device__ __forceinline__ float sigf(float x) {
    return 1.0f / (1.0f + __expf(-x));
}
__device__ __forceinline__ float tanhfast(float x) {
    return 1.0f - 2.0f / (__expf(2.0f * x) + 1.0f);
}

__device__ __forceinline__ void vm0() {
    asm volatile("s_waitcnt vmcnt(0)" ::: "memory");
}
// LDS counter: lane0 of the wave increments (release: orders prior LDS+reg work)
__device__ __forceinline__ void ds_inc(int* c) {
    if ((threadIdx.x & 63) == 0)
        __hip_atomic_fetch_add(c, 1, __ATOMIC_RELEASE, WG);
}
// lane0 of the wave polls; whole wave blocks until it exits (exec-mask loop)
__device__ __forceinline__ void ds_pollw(int* c, int target) {
    if ((threadIdx.x & 63) == 0)
        while (__hip_atomic_load(c, __ATOMIC_ACQUIRE, WG) < target) {}
}
// per-wave global flag poll: lanes 0..7 watch the 8 sub-counters of one line
__device__ __forceinline__ void gwaitw(const int* base, int target) {
    int l = threadIdx.x & 63;
    if (l < 8)
        while (__hip_atomic_load(base + l, __ATOMIC_RELAXED, AGENT) < target)
            __builtin_amdgcn_s_sleep(2);
}

// ---------------- prep kernels ----------------
__global__ void prep_w(const float* __restrict__ Wx, const float* __restrict__ Wh,
                       const float* __restrict__ Wd,
                       _Float16* __restrict__ WfullT, _Float16* __restrict__ WdT) {
    int bid = blockIdx.x;
    if (bid < 4096) {
        int n = bid;
        for (int k = threadIdx.x; k < KF; k += 256) {
            float v;
            if (k < 256)       v = Wx[(size_t)k * 4096 + n];
            else if (k < 1280) v = Wh[(size_t)(k - 256) * 4096 + n];
            else               v = Wx[(size_t)(k - 1024) * 4096 + n];
            WfullT[(size_t)n * KF + k] = (_Float16)v;
        }
    } else {
        int o = bid - 4096;
        for (int k = threadIdx.x; k < HID; k += 256) {
            WdT[(size_t)o * HID + k] = (_Float16)Wd[(size_t)k * OUTD + o];
        }
    }
}

__global__ void prep_x(const float* __restrict__ x, _Float16* __restrict__ xh, int* cnts) {
    size_t i0 = ((size_t)blockIdx.x * 256 + threadIdx.x) * 8;
    float4 a = *(const float4*)(x + i0);
    float4 c = *(const float4*)(x + i0 + 4);
    f16x8 v;
    v[0] = (_Float16)a.x; v[1] = (_Float16)a.y; v[2] = (_Float16)a.z; v[3] = (_Float16)a.w;
    v[4] = (_Float16)c.x; v[5] = (_Float16)c.y; v[6] = (_Float16)c.z; v[7] = (_Float16)c.w;
    *(f16x8*)(xh + i0) = v;
    if (blockIdx.x == 0) cnts[threadIdx.x] = 0;   // zero 1KB counter region
}

// ---------------- GEMM part (R7): NS K-steps of 4 MFMAs, M=32/wave ----------------
template<int NS, typename AL>
__device__ __forceinline__ void gemmPart(AL&& aload, const _Float16* slab, int kbB,
                                         int rl, int kg, f32x4 (&acc)[2][2]) {
    constexpr int PFD = (NS < 12) ? NS : 12;
    f16x8 pa[PFD][2];
#pragma unroll
    for (int i = 0; i < PFD; ++i) { pa[i][0] = aload(i, 0); pa[i][1] = aload(i, 1); }
    const int sw = rl & 7;
    const _Float16* bb0 = slab + (size_t)rl * 1536;
    const _Float16* bb1 = slab + (size_t)(16 + rl) * 1536;
#pragma unroll
    for (int kk = 0; kk < NS; ++kk) {
        int kblk = kbB + kk * 4 + kg;
        int idx = (kblk ^ sw) * 8;
        f16x8 b0 = *(const f16x8*)(bb0 + idx);
        f16x8 b1 = *(const f16x8*)(bb1 + idx);
        f16x8 a0 = pa[kk % PFD][0];
        f16x8 a1 = pa[kk % PFD][1];
        if (kk + PFD < NS) {
            pa[kk % PFD][0] = aload(kk + PFD, 0);
            pa[kk % PFD][1] = aload(kk + PFD, 1);
        }
        acc[0][0] = __builtin_amdgcn_mfma_f32_16x16x32_f16(a0, b0, acc[0][0], 0, 0, 0);
        acc[0][1] = __builtin_amdgcn_mfma_f32_16x16x32_f16(a0, b1, acc[0][1], 0, 0, 0);
        acc[1][0] = __builtin_amdgcn_mfma_f32_16x16x32_f16(a1, b0, acc[1][0], 0, 0, 0);
        acc[1][1] = __builtin_amdgcn_mfma_f32_16x16x32_f16(a1, b1, acc[1][1], 0, 0, 0);
    }
}

// ---------------- persistent LSTM ----------------
// 512 threads = 8 waves. Waves 0-3: phase A (R7 core, 32 rows/wave) + epilogue.
// Waves 4-7: phase B (K slice 256/wave). Group g = bid>>7 self-contained.
__global__ __launch_bounds__(512, 2) void lstm_persist(
        const _Float16* __restrict__ WfullT, const _Float16* __restrict__ WdT,
        const _Float16* __restrict__ xh, const float* __restrict__ b,
        const float* __restrict__ bd,
        _Float16* __restrict__ ring,
        int* cnts, float* __restrict__ out) {
    extern __shared__ char dynsm[];
    _Float16* slab = (_Float16*)dynsm;                              // [32][192][8]
    _Float16* wdt  = (_Float16*)(dynsm + LDS_SLAB);                 // [16][128][8]
    float* zbuf = (float*)(dynsm + LDS_SLAB + LDS_WDT);             // [128][33]
    float* red  = (float*)(dynsm + LDS_SLAB + LDS_WDT + LDS_ZBUF);  // [4][256]
    unsigned short* ys = (unsigned short*)(dynsm + LDS_SLAB + LDS_WDT + LDS_ZBUF + LDS_RED);
    int* sy = (int*)(dynsm + LDS_SLAB + LDS_WDT + LDS_ZBUF + LDS_RED + LDS_YS);

    const int tid = threadIdx.x, bid = blockIdx.x;
    const int w = tid >> 6, lane = tid & 63;
    const int rl = lane & 15, kg = lane >> 4;

    const int bat0 = (bid >> 7) << 7;
    const int n0 = (bid & 127) << 3;
    const int r0 = (bid >> 4) << 4;
    const int c0 = (bid & 15) << 4;
    const int gid = bid >> 7;
    const int subj = (bid >> 4) & 7;

    int* hcnt = cnts + HCNT(gid);
    int* ycnt = cnts + YCNT(gid);

    // ---- init: weight slab + WdT tile (swizzled) into LDS; sync ctrs ----
    for (int i = tid; i < 32 * 192; i += 512) {
        int vcol = i / 192, kblk = i % 192;
        int n = (vcol & 3) * 1024 + n0 + (vcol >> 2);
        f16x8 v = *(const f16x8*)(WfullT + (size_t)n * KF + kblk * 8);
        *(f16x8*)(slab + ((size_t)vcol * 192 + (kblk ^ (vcol & 7))) * 8) = v;
    }
    for (int i = tid; i < 16 * 128; i += 512) {
        int wcol = i >> 7, kb = i & 127;
        f16x8 v = *(const f16x8*)(WdT + (size_t)(c0 + wcol) * HID + kb * 8);
        *(f16x8*)(wdt + ((size_t)wcol * 128 + (kb ^ (wcol & 7))) * 8) = v;
    }
    if (tid < 16) sy[tid] = 0;

    // R7 epilogue mapping (tid<256 == waves 0-3)
    const int trow = tid >> 1;
    const int ccB = (tid & 1) * 4;
    float bb[4][4];
    if (w < 4) {
#pragma unroll
        for (int g = 0; g < 4; ++g)
#pragma unroll
            for (int c2 = 0; c2 < 4; ++c2)
                bb[g][c2] = b[g * 1024 + n0 + ccB + c2];
    }
    const float bdv = bd[c0 + (tid & 15)];
    float creg[4] = {0.f, 0.f, 0.f, 0.f};

    // ---- init grid barrier (block-wide syncthreads OK before role split) ----
    __syncthreads();
    if (tid == 0)
        __hip_atomic_fetch_add(hcnt + subj, 1, __ATOMIC_RELAXED, AGENT);
    if (tid < 8) {
        while (__hip_atomic_load(cnts + HCNT(0) + tid, __ATOMIC_RELAXED, AGENT) < 16 ||
               __hip_atomic_load(cnts + HCNT(1) + tid, __ATOMIC_RELAXED, AGENT) < 16)
            __builtin_amdgcn_s_sleep(2);
    }
    __syncthreads();

    if (w < 4) {
        // ================= producer waves (0-3): phase A + epilogue =================
        const size_t arow = (size_t)(bat0 + w * 32 + rl);
        int zsT = 0, hsT = 0;

        // epilogue: acc -> zbuf -> gates -> c,h -> slotW; announce h
        auto epilogue = [&](f32x4 (&A)[2][2], _Float16* slotW, int hEpochTarget) {
#pragma unroll
            for (int mt = 0; mt < 2; ++mt)
#pragma unroll
                for (int nt = 0; nt < 2; ++nt)
#pragma unroll
                    for (int r = 0; r < 4; ++r) {
                        int zrow = w * 32 + mt * 16 + kg * 4 + r;
                        zbuf[zrow * 33 + nt * 16 + rl] = A[mt][nt][r];
                    }
            zsT += 4;
            ds_inc(sy + SY_ZS);
            ds_pollw(sy + SY_ZS, zsT);
            union { f16x4 v; unsigned long long u; } hu;
#pragma unroll
            for (int c2 = 0; c2 < 4; ++c2) {
                int cc = ccB + c2;
                float zi = zbuf[trow * 33 + cc * 4 + 0];
                float zf = zbuf[trow * 33 + cc * 4 + 1];
                float zg = zbuf[trow * 33 + cc * 4 + 2];
                float zo = zbuf[trow * 33 + cc * 4 + 3];
                float iv = sigf(zi + bb[0][c2]);
                float fv = sigf(zf + bb[1][c2]);
                float gv = tanhfast(zg + bb[2][c2]);
                float ov = sigf(zo + bb[3][c2]);
                float cnew = fv * creg[c2] + iv * gv;
                creg[c2] = cnew;
                hu.v[c2] = (_Float16)(ov * tanhfast(cnew));
            }
            __hip_atomic_store(
                (unsigned long long*)(slotW + (size_t)(bat0 + trow) * KA + n0 + ccB),
                hu.u, __ATOMIC_RELAXED, AGENT);
            vm0();
            hsT += 4;
            ds_inc(sy + SY_HS);
            if (tid == 0) {
                while (__hip_atomic_load(sy + SY_HS, __ATOMIC_ACQUIRE, WG) < hsT) {}
                __hip_atomic_fetch_add(hcnt + subj, 1, __ATOMIC_RELAXED, AGENT);
            }
            (void)hEpochTarget;
        };

        f32x4 acc[2][2];
        // ---- t = 0: x-only GEMM (h=c=y=0), h_0 -> slot 0 ----
#pragma unroll
        for (int mt = 0; mt < 2; ++mt)
#pragma unroll
            for (int nt = 0; nt < 2; ++nt) {
                acc[mt][nt][0] = 0.f; acc[mt][nt][1] = 0.f;
                acc[mt][nt][2] = 0.f; acc[mt][nt][3] = 0.f;
            }
        {
            const _Float16* xb = xh + arow * 65536 + kg * 8;
            auto loadX = [&](int kk, int mt) -> f16x8 {
                return *(const f16x8*)(xb + (size_t)mt * 16 * 65536 + kk * 32);
            };
            gemmPart<8>(loadX, slab, 0, rl, kg, acc);
        }
        epilogue(acc, ring, 2);   // announce h_0 -> hcnt 32

        // ---- steady: compute z_{tt+1}, h_{tt+1} for tt = 0..254 ----
        for (int tt = 0; tt < TSTEPS - 1; ++tt) {
            if ((tt & 15) == 0)
                __builtin_amdgcn_fence(__ATOMIC_ACQUIRE, "agent");

            const _Float16* slotT = ring + (size_t)(tt & (RSLOTS - 1)) * SLOTE;
            _Float16* slotW = ring + (size_t)((tt + 1) & (RSLOTS - 1)) * SLOTE;

#pragma unroll
            for (int mt = 0; mt < 2; ++mt)
#pragma unroll
                for (int nt = 0; nt < 2; ++nt) {
                    acc[mt][nt][0] = 0.f; acc[mt][nt][1] = 0.f;
                    acc[mt][nt][2] = 0.f; acc[mt][nt][3] = 0.f;
                }

            {   // xGEMM(tt+1) — independent filler before wait-h
                const _Float16* xb = xh + arow * 65536 + (size_t)(tt + 1) * 256 + kg * 8;
                auto loadX = [&](int kk, int mt) -> f16x8 {
                    return *(const f16x8*)(xb + (size_t)mt * 16 * 65536 + kk * 32);
                };
                gemmPart<8>(loadX, slab, 0, rl, kg, acc);
            }

            gwaitw(hcnt, (tt + 2) * 16);        // h_tt visible

            {   // hGEMM(tt+1) — y_tt propagation (other waves) hides under this
                const _Float16* hb = slotT + arow * KA + kg * 8;
                auto loadH = [&](int kk, int mt) -> f16x8 {
                    return *(const f16x8*)(hb + (size_t)mt * 16 * KA + kk * 32);
                };
                gemmPart<32>(loadH, slab, 32, rl, kg, acc);
            }

            gwaitw(ycnt, (tt + 1) * 16);        // y_tt visible

            {   // yGEMM(tt+1)
                const _Float16* yb = slotT + arow * KA + 1024 + kg * 8;
                auto loadY = [&](int kk, int mt) -> f16x8 {
                    return *(const f16x8*)(yb + (size_t)mt * 16 * KA + kk * 32);
                };
                gemmPart<8>(loadY, slab, 160, rl, kg, acc);
            }

            epilogue(acc, slotW, tt + 3);       // h_{tt+1} -> hcnt (tt+3)*16
        }
    } else {
        // ================= consumer waves (4-7): phase B =================
        const int w2 = w - 4;
        const int tid2 = tid - 256;             // 0..255
        int p1T = 0, p2T = 0, yaT = 0;

        for (int t = 0; t < TSTEPS; ++t) {
            if ((t & 15) == 0)
                __builtin_amdgcn_fence(__ATOMIC_ACQUIRE, "agent");

            _Float16* slotT = ring + (size_t)(t & (RSLOTS - 1)) * SLOTE;

            // hoist Wd fragments (independent of the wait)
            f16x8 wa[8];
#pragma unroll
            for (int it = 0; it < 8; ++it) {
                int kb = (w2 << 5) + it * 4 + kg;
                wa[it] = *(const f16x8*)(wdt + ((size_t)rl * 128 + (kb ^ (rl & 7))) * 8);
            }

            gwaitw(hcnt, (t + 2) * 16);         // h_t visible

            {   // K-sliced h @ Wd partial
                const _Float16* hp = slotT + (size_t)(r0 + rl) * KA + (w2 << 8) + kg * 8;
                f16x8 ha[8];
#pragma unroll
                for (int it = 0; it < 8; ++it)
                    ha[it] = *(const f16x8*)(hp + it * 32);
                f32x4 accB; accB[0] = 0.f; accB[1] = 0.f; accB[2] = 0.f; accB[3] = 0.f;
#pragma unroll
                for (int it = 0; it < 8; ++it)
                    accB = __builtin_amdgcn_mfma_f32_16x16x32_f16(ha[it], wa[it], accB, 0, 0, 0);
#pragma unroll
                for (int r = 0; r < 4; ++r)
                    red[w2 * 256 + (kg * 4 + r) * 16 + rl] = accB[r];
            }
            p1T += 4;
            ds_inc(sy + SY_P1);
            ds_pollw(sy + SY_P1, p1T);

            {   // reduce 4 K-slices, tanh, out + ys
                int rr = tid2 >> 4, cc = tid2 & 15;
                float s = red[rr * 16 + cc] + red[256 + rr * 16 + cc] +
                          red[512 + rr * 16 + cc] + red[768 + rr * 16 + cc];
                float y = tanhfast(s + bdv);
                __builtin_nontemporal_store(
                    y, out + (size_t)(r0 + rr) * 65536 + (size_t)t * 256 + (c0 + cc));
                union { _Float16 h; unsigned short u; } cv; cv.h = (_Float16)y;
                ys[tid2] = cv.u;
            }
            p2T += 4;
            ds_inc(sy + SY_P2);
            ds_pollw(sy + SY_P2, p2T);

            if (tid2 < 64) {   // y -> ring (8B sc1 stores)
                unsigned long long yv = *(const unsigned long long*)(ys + tid2 * 4);
                int row = r0 + (tid2 >> 2), colb = c0 + (tid2 & 3) * 4;
                __hip_atomic_store(
                    (unsigned long long*)(slotT + (size_t)row * KA + 1024 + colb),
                    yv, __ATOMIC_RELAXED, AGENT);
            }
            vm0();
            yaT += 4;
            ds_inc(sy + SY_YA);
            if (tid2 == 0) {
                while (__hip_atomic_load(sy + SY_YA, __ATOMIC_ACQUIRE, WG) < yaT) {}
                __hip_atomic_fetch_add(ycnt + subj, 1, __ATOMIC_RELAXED, AGENT);
            }
        }
    }
}

extern "C" void kernel_launch(void* const* d_in, const int* in_sizes, int n_in,
                              void* d_out, int out_size, void* d_ws, size_t ws_size,
                              hipStream_t stream) {
    const float* x  = (const float*)d_in[0];
    const float* Wx = (const float*)d_in[1];
    const float* Wh = (const float*)d_in[2];
    const float* b  = (const float*)d_in[3];
    const float* Wd = (const float*)d_in[4];
    const float* bd = (const float*)d_in[5];
    float* out = (float*)d_out;
    char* ws = (char*)d_ws;
    if (ws_size < WS_NEEDED) return;

    _Float16* WfullT = (_Float16*)(ws + WFULLT_OFF);
    _Float16* WdT    = (_Float16*)(ws + WDT_OFF);
    _Float16* xh     = (_Float16*)(ws + XH_OFF);
    _Float16* ring   = (_Float16*)(ws + RING_OFF);
    int*      cnts   = (int*)(ws + CNT_OFF);

    static int lds_set = 0;
    if (!lds_set) {
        hipFuncSetAttribute((const void*)lstm_persist,
                            hipFuncAttributeMaxDynamicSharedMemorySize, LDS_TOTAL);
        lds_set = 1;
    }

    prep_w<<<4352, 256, 0, stream>>>(Wx, Wh, Wd, WfullT, WdT);
    prep_x<<<8192, 256, 0, stream>>>(x, xh, cnts);
    lstm_persist<<<NBLK, 512, LDS_TOTAL, stream>>>(WfullT, WdT, xh, b, bd, ring, cnts, out);
}

// Round 11
// 3913.519 us; speedup vs baseline: 1.6841x; 1.6841x over previous
//
#include <hip/hip_runtime.h>

// Autoregressive LSTM on MI355X (gfx950).
// B=256, T=256, D=256, H=1024, O=256.
// Persistent 256-block kernel; weights LDS-resident; fence-free steady state
// (sc1 write-through stores + 16-slot ring + acquire fence every 16 steps);
// two independent 128-block groups; software-pipelined step loop.
// Round 11 (on R9 base): per-block rotated K-traversal ((bid>>3)&7 — varies
// WITHIN an XCD) so the 32 same-XCD blocks cold-fill 8 different panel chunks
// in parallel instead of queueing on the same lines; prefetch depth 12->16.

typedef _Float16 f16x8 __attribute__((ext_vector_type(8)));
typedef _Float16 f16x4 __attribute__((ext_vector_type(4)));
typedef float f32x4 __attribute__((ext_vector_type(4)));

#define TSTEPS 256
#define HID 1024
#define OUTD 256
#define KF 1536            // D + H + O (WfullT K)
#define KA 1280            // ring row: h[0..1024) | y[1024..1280)
#define NBLK 256
#define RSLOTS 16
#define SLOTE (256 * KA)   // elements per ring slot

// workspace layout (bytes)
#define RING_OFF   0ull                       // fp16 16*256*1280 = 10,485,760 (aliases WfullT)
#define WFULLT_OFF 0ull                       // fp16 [4096][1536] = 12,582,912 (init-only)
#define WDT_OFF    12582912ull                // fp16 [256][1024]  = 524,288
#define XH_OFF     13107200ull                // fp16 [256][256][256] = 33,554,432
#define CNT_OFF    46661632ull                // sub-counters (1KB region)
#define WS_NEEDED  46663680ull

// counter layout (ints): hcnt grp0 @0..8, grp1 @64..72; ycnt grp0 @128..136, grp1 @192..200
#define HCNT(g) ((g) * 64)
#define YCNT(g) (128 + (g) * 64)

#define LDS_SLAB_BYTES 98304                  // 32 vcols * 192 kblks * 16B
#define LDS_WDT_BYTES  32768                  // 16 cols * 128 kblks * 16B
#define LDS_ZBUF_BYTES 16896                  // [128][33] f32
#define LDS_TOTAL (LDS_SLAB_BYTES + LDS_WDT_BYTES + LDS_ZBUF_BYTES)

#define AGENT  __HIP_MEMORY_SCOPE_AGENT

__device__ __forceinline__ float sigf(float x) {
    return 1.0f / (1.0f + __expf(-x));
}
__device__ __forceinline__ float tanhfast(float x) {
    return 1.0f - 2.0f / (__expf(2.0f * x) + 1.0f);
}

// ---- sub-counter barrier (one 64B line per group/type) ----
__device__ __forceinline__ void garrive(int* base, int j) {
    __syncthreads();   // vmcnt(0): all sc1 data stores retired at coherence point
    if (threadIdx.x == 0)
        __hip_atomic_fetch_add(base + j, 1, __ATOMIC_RELAXED, AGENT);
}
__device__ __forceinline__ void gwait(int* base, int target) {
    if (threadIdx.x < 8) {
        while (__hip_atomic_load(base + threadIdx.x, __ATOMIC_RELAXED, AGENT) < target)
            __builtin_amdgcn_s_sleep(2);
    }
    __syncthreads();
}
__device__ __forceinline__ void gwait_both(int* cnts, int target) {
    if (threadIdx.x < 8) {
        while (__hip_atomic_load(cnts + HCNT(0) + threadIdx.x, __ATOMIC_RELAXED, AGENT) < target ||
               __hip_atomic_load(cnts + HCNT(1) + threadIdx.x, __ATOMIC_RELAXED, AGENT) < target)
            __builtin_amdgcn_s_sleep(2);
    }
    __syncthreads();
}

// ---------------- prep kernels ----------------
__global__ void prep_w(const float* __restrict__ Wx, const float* __restrict__ Wh,
                       const float* __restrict__ Wd,
                       _Float16* __restrict__ WfullT, _Float16* __restrict__ WdT) {
    int bid = blockIdx.x;
    if (bid < 4096) {
        int n = bid;
        for (int k = threadIdx.x; k < KF; k += 256) {
            float v;
            if (k < 256)       v = Wx[(size_t)k * 4096 + n];
            else if (k < 1280) v = Wh[(size_t)(k - 256) * 4096 + n];
            else               v = Wx[(size_t)(k - 1024) * 4096 + n];
            WfullT[(size_t)n * KF + k] = (_Float16)v;
        }
    } else {
        int o = bid - 4096;
        for (int k = threadIdx.x; k < HID; k += 256) {
            WdT[(size_t)o * HID + k] = (_Float16)Wd[(size_t)k * OUTD + o];
        }
    }
}

__global__ void prep_x(const float* __restrict__ x, _Float16* __restrict__ xh, int* cnts) {
    size_t i0 = ((size_t)blockIdx.x * 256 + threadIdx.x) * 8;
    float4 a = *(const float4*)(x + i0);
    float4 c = *(const float4*)(x + i0 + 4);
    f16x8 v;
    v[0] = (_Float16)a.x; v[1] = (_Float16)a.y; v[2] = (_Float16)a.z; v[3] = (_Float16)a.w;
    v[4] = (_Float16)c.x; v[5] = (_Float16)c.y; v[6] = (_Float16)c.z; v[7] = (_Float16)c.w;
    *(f16x8*)(xh + i0) = v;
    if (blockIdx.x == 0) cnts[threadIdx.x] = 0;   // zero 1KB counter region
}

// ---------------- GEMM part: NS K-steps of 2 MFMAs, rotated traversal ----------------
// One M-tile (16 rows) per wave, 2 N-tiles (32 vcols). K-order starts at
// kk-offset `rot` (mod NS via MASK) so different blocks fill different
// panel chunks first. FP32 accumulate -> order only changes rounding.
template<int NS, int MASK, typename AL>
__device__ __forceinline__ void gemmPartR(AL&& aload, const _Float16* slab, int kbB,
                                          int rot, int rl, int kg, f32x4 (&acc)[2]) {
    constexpr int PFD = (NS < 16) ? NS : 16;
    f16x8 pa[PFD];
#pragma unroll
    for (int i = 0; i < PFD; ++i) pa[i] = aload((i + rot) & MASK);
    const int sw = rl & 7;
    const _Float16* bb0 = slab + (size_t)rl * 1536;
    const _Float16* bb1 = slab + (size_t)(16 + rl) * 1536;
#pragma unroll
    for (int kk = 0; kk < NS; ++kk) {
        int pos = (kk + rot) & MASK;
        int kblk = kbB + pos * 4 + kg;
        int idx = (kblk ^ sw) * 8;
        f16x8 b0 = *(const f16x8*)(bb0 + idx);
        f16x8 b1 = *(const f16x8*)(bb1 + idx);
        f16x8 a0 = pa[kk % PFD];
        if (kk + PFD < NS) pa[kk % PFD] = aload((kk + PFD + rot) & MASK);
        acc[0] = __builtin_amdgcn_mfma_f32_16x16x32_f16(a0, b0, acc[0], 0, 0, 0);
        acc[1] = __builtin_amdgcn_mfma_f32_16x16x32_f16(a0, b1, acc[1], 0, 0, 0);
    }
}

// ---------------- persistent LSTM ----------------
// 512 threads = 8 waves; phase A: wave w owns batch rows bat0 + w*16 .. +16.
// Epilogue + phase B: Round-7 code on tid<256 (4 waves), w<4 for phase-B MFMA.
__global__ __launch_bounds__(512, 2) void lstm_persist(
        const _Float16* __restrict__ WfullT, const _Float16* __restrict__ WdT,
        const _Float16* __restrict__ xh, const float* __restrict__ b,
        const float* __restrict__ bd,
        _Float16* __restrict__ ring,
        int* cnts, float* __restrict__ out) {
    extern __shared__ char dynsm[];
    _Float16* slab = (_Float16*)dynsm;                              // [32][192][8]
    _Float16* wdt  = (_Float16*)(dynsm + LDS_SLAB_BYTES);           // [16][128][8]
    float* zbuf = (float*)(dynsm + LDS_SLAB_BYTES + LDS_WDT_BYTES); // [128][33]

    const int tid = threadIdx.x, bid = blockIdx.x;
    const int w = tid >> 6, lane = tid & 63;
    const int rl = lane & 15, kg = lane >> 4;

    const int bat0 = (bid >> 7) << 7;
    const int n0 = (bid & 127) << 3;
    const int r0 = (bid >> 4) << 4;
    const int c0 = (bid & 15) << 4;
    const int gid = bid >> 7;
    const int subj = (bid >> 4) & 7;      // 16 blocks per sub-counter
    const int rotS = (bid >> 3) & 7;      // varies WITHIN an XCD (bid%8 = XCD)
    const int rotL = rotS * 4;            // chunk rotation for NS=32 (4 kk/chunk)

    int* hcnt = cnts + HCNT(gid);
    int* ycnt = cnts + YCNT(gid);

    // ---- init: weight slab + WdT tile (swizzled) into LDS ----
    for (int i = tid; i < 32 * 192; i += 512) {
        int vcol = i / 192, kblk = i % 192;
        int n = (vcol & 3) * 1024 + n0 + (vcol >> 2);
        f16x8 v = *(const f16x8*)(WfullT + (size_t)n * KF + kblk * 8);
        *(f16x8*)(slab + ((size_t)vcol * 192 + (kblk ^ (vcol & 7))) * 8) = v;
    }
    for (int i = tid; i < 16 * 128; i += 512) {
        int wcol = i >> 7, kb = i & 127;
        f16x8 v = *(const f16x8*)(WdT + (size_t)(c0 + wcol) * HID + kb * 8);
        *(f16x8*)(wdt + ((size_t)wcol * 128 + (kb ^ (wcol & 7))) * 8) = v;
    }
    // R7 epilogue mapping (tid<256 active)
    const int trow = tid >> 1;          // 0..127 for tid<256
    const int ccB = (tid & 1) * 4;      // 0 or 4
    float bb[4][4];
#pragma unroll
    for (int g = 0; g < 4; ++g)
#pragma unroll
        for (int c2 = 0; c2 < 4; ++c2)
            bb[g][c2] = b[g * 1024 + n0 + ((ccB + c2) & 7)];
    const float bdv = bd[c0 + (tid & 15)];
    float creg[4] = {0.f, 0.f, 0.f, 0.f};

    const size_t arow = (size_t)(bat0 + w * 16 + rl);

    // epilogue: acc(z) -> zbuf; R7 gate/c/h path on tid<256; h -> slotW (sc1)
    auto epilogue = [&](f32x4 (&A)[2], _Float16* slotW) {
#pragma unroll
        for (int nt = 0; nt < 2; ++nt)
#pragma unroll
            for (int r = 0; r < 4; ++r) {
                int zrow = w * 16 + kg * 4 + r;
                zbuf[zrow * 33 + nt * 16 + rl] = A[nt][r];
            }
        __syncthreads();
        if (tid < 256) {
            union { f16x4 v; unsigned long long u; } hu;
#pragma unroll
            for (int c2 = 0; c2 < 4; ++c2) {
                int cc = ccB + c2;
                float zi = zbuf[trow * 33 + cc * 4 + 0];
                float zf = zbuf[trow * 33 + cc * 4 + 1];
                float zg = zbuf[trow * 33 + cc * 4 + 2];
                float zo = zbuf[trow * 33 + cc * 4 + 3];
                float iv = sigf(zi + bb[0][c2]);
                float fv = sigf(zf + bb[1][c2]);
                float gv = tanhfast(zg + bb[2][c2]);
                float ov = sigf(zo + bb[3][c2]);
                float cnew = fv * creg[c2] + iv * gv;
                creg[c2] = cnew;
                hu.v[c2] = (_Float16)(ov * tanhfast(cnew));
            }
            __hip_atomic_store(
                (unsigned long long*)(slotW + (size_t)(bat0 + trow) * KA + n0 + ccB),
                hu.u, __ATOMIC_RELAXED, AGENT);
        }
    };

    // phase B (R7): waves 0-3 compute, K slice 256/wave; y -> out (NT) + slotT
    auto phaseB = [&](int t, _Float16* slotT, const f16x8* wa) {
        float* red = zbuf;
        if (w < 4) {
            const _Float16* hp = slotT + (size_t)(r0 + rl) * KA + (w << 8) + kg * 8;
            f16x8 ha[8];
#pragma unroll
            for (int it = 0; it < 8; ++it)
                ha[it] = *(const f16x8*)(hp + it * 32);
            f32x4 accB; accB[0] = 0.f; accB[1] = 0.f; accB[2] = 0.f; accB[3] = 0.f;
#pragma unroll
            for (int it = 0; it < 8; ++it)
                accB = __builtin_amdgcn_mfma_f32_16x16x32_f16(ha[it], wa[it], accB, 0, 0, 0);
#pragma unroll
            for (int r = 0; r < 4; ++r)
                red[w * 256 + (kg * 4 + r) * 16 + rl] = accB[r];
        }
        __syncthreads();
        unsigned short* ys = (unsigned short*)(zbuf + 1024);
        if (tid < 256) {
            int rr = tid >> 4, cc = tid & 15;
            float s = red[rr * 16 + cc] + red[256 + rr * 16 + cc] +
                      red[512 + rr * 16 + cc] + red[768 + rr * 16 + cc];
            float y = tanhfast(s + bdv);
            __builtin_nontemporal_store(
                y, out + (size_t)(r0 + rr) * 65536 + (size_t)t * 256 + (c0 + cc));
            union { _Float16 h; unsigned short u; } cv; cv.h = (_Float16)y;
            ys[tid] = cv.u;
        }
        __syncthreads();
        if (tid < 64) {
            unsigned long long yv = *(const unsigned long long*)(ys + tid * 4);
            int row = r0 + (tid >> 2), colb = c0 + (tid & 3) * 4;
            __hip_atomic_store(
                (unsigned long long*)(slotT + (size_t)row * KA + 1024 + colb),
                yv, __ATOMIC_RELAXED, AGENT);
        }
    };

    // ---- init barrier: all WfullT reads complete before ring overwrites it ----
    garrive(hcnt, subj);            // epoch 1 (target 16 per sub-counter)
    gwait_both(cnts, 16);

    // ---- t = 0: x-only GEMM (h=c=y=0), h_0 -> slot 0 ----
    f32x4 acc[2];
    acc[0][0] = 0.f; acc[0][1] = 0.f; acc[0][2] = 0.f; acc[0][3] = 0.f;
    acc[1][0] = 0.f; acc[1][1] = 0.f; acc[1][2] = 0.f; acc[1][3] = 0.f;
    {
        const _Float16* xb = xh + arow * 65536 + kg * 8;
        auto loadX = [&](int kk) -> f16x8 {
            return *(const f16x8*)(xb + kk * 32);
        };
        gemmPartR<8, 7>(loadX, slab, 0, rotS, rl, kg, acc);
    }
    epilogue(acc, ring);
    garrive(hcnt, subj);            // h_0 announced (epoch 2)

    // ---- pipelined steady loop ----
    for (int t = 0; t < TSTEPS; ++t) {
        // ring-wrap staleness fence (reuse distance = 16 slots)
        if ((t & 15) == 0)
            __builtin_amdgcn_fence(__ATOMIC_ACQUIRE, "agent");

        _Float16* slotT = ring + (size_t)(t & (RSLOTS - 1)) * SLOTE;

        acc[0][0] = 0.f; acc[0][1] = 0.f; acc[0][2] = 0.f; acc[0][3] = 0.f;
        acc[1][0] = 0.f; acc[1][1] = 0.f; acc[1][2] = 0.f; acc[1][3] = 0.f;

        if (t < TSTEPS - 1) {   // xGEMM(t+1) — hides h_t flag propagation
            const _Float16* xb = xh + arow * 65536 + (size_t)(t + 1) * 256 + kg * 8;
            auto loadX = [&](int kk) -> f16x8 {
                return *(const f16x8*)(xb + kk * 32);
            };
            gemmPartR<8, 7>(loadX, slab, 0, rotS, rl, kg, acc);
        }

        // preload phase-B Wd fragments from LDS (R7 indexing; used by w<4)
        f16x8 wa[8];
#pragma unroll
        for (int it = 0; it < 8; ++it) {
            int kb = ((w & 3) << 5) + it * 4 + kg;
            wa[it] = *(const f16x8*)(wdt + ((size_t)rl * 128 + (kb ^ (rl & 7))) * 8);
        }

        gwait(hcnt, (t + 2) * 16);          // h_t visible group-wide
        phaseB(t, slotT, wa);               // y_t -> out + ring

        if (t < TSTEPS - 1) {
            garrive(ycnt, subj);            // y_t announced (epoch t+1)

            {   // hGEMM(t+1) reading h_t — rotated K so same-XCD blocks
                // fill different 128-col chunks of the panel in parallel
                const _Float16* hb = slotT + arow * KA + kg * 8;
                auto loadH = [&](int kk) -> f16x8 {
                    return *(const f16x8*)(hb + kk * 32);
                };
                gemmPartR<32, 31>(loadH, slab, 32, rotL, rl, kg, acc);
            }

            gwait(ycnt, (t + 1) * 16);      // y_t visible group-wide

            {   // yGEMM(t+1), rotated
                const _Float16* yb = slotT + arow * KA + 1024 + kg * 8;
                auto loadY = [&](int kk) -> f16x8 {
                    return *(const f16x8*)(yb + kk * 32);
                };
                gemmPartR<8, 7>(loadY, slab, 160, rotS, rl, kg, acc);
            }

            epilogue(acc, ring + (size_t)((t + 1) & (RSLOTS - 1)) * SLOTE);
            garrive(hcnt, subj);            // h_{t+1} announced (epoch t+3)
        }
    }
}

extern "C" void kernel_launch(void* const* d_in, const int* in_sizes, int n_in,
                              void* d_out, int out_size, void* d_ws, size_t ws_size,
                              hipStream_t stream) {
    const float* x  = (const float*)d_in[0];
    const float* Wx = (const float*)d_in[1];
    const float* Wh = (const float*)d_in[2];
    const float* b  = (const float*)d_in[3];
    const float* Wd = (const float*)d_in[4];
    const float* bd = (const float*)d_in[5];
    float* out = (float*)d_out;
    char* ws = (char*)d_ws;
    if (ws_size < WS_NEEDED) return;

    _Float16* WfullT = (_Float16*)(ws + WFULLT_OFF);
    _Float16* WdT    = (_Float16*)(ws + WDT_OFF);
    _Float16* xh     = (_Float16*)(ws + XH_OFF);
    _Float16* ring   = (_Float16*)(ws + RING_OFF);
    int*      cnts   = (int*)(ws + CNT_OFF);

    static int lds_set = 0;
    if (!lds_set) {
        hipFuncSetAttribute((const void*)lstm_persist,
                            hipFuncAttributeMaxDynamicSharedMemorySize, LDS_TOTAL);
        lds_set = 1;
    }

    prep_w<<<4352, 256, 0, stream>>>(Wx, Wh, Wd, WfullT, WdT);
    prep_x<<<8192, 256, 0, stream>>>(x, xh, cnts);
    lstm_persist<<<NBLK, 512, LDS_TOTAL, stream>>>(WfullT, WdT, xh, b, bd, ring, cnts, out);
}

// Round 14
// 3906.626 us; speedup vs baseline: 1.6870x; 1.0018x over previous
//
#include <hip/hip_runtime.h>

// Autoregressive LSTM on MI355X (gfx950).
// B=256, T=256, D=256, H=1024, O=256.
// Persistent 256-block kernel; weights LDS-resident; fence-free steady state
// (sc1 write-through stores + 16-slot ring + acquire fence every 16 steps);
// two independent 128-block groups; software-pipelined step loop.
// Round 14 = revert to Round 11 (best passing, 3913 us). R12/R13's
// dependency-exact waits race on producer-side fabric ordering (sc1 data
// stores vs flag RMW to different MALL banks); fixing needs release/acquire
// fences costing more than the saving (R3 evidence). This is the structural
// floor of the 128-block exchange topology forced by LDS capacity.

typedef _Float16 f16x8 __attribute__((ext_vector_type(8)));
typedef _Float16 f16x4 __attribute__((ext_vector_type(4)));
typedef float f32x4 __attribute__((ext_vector_type(4)));

#define TSTEPS 256
#define HID 1024
#define OUTD 256
#define KF 1536            // D + H + O (WfullT K)
#define KA 1280            // ring row: h[0..1024) | y[1024..1280)
#define NBLK 256
#define RSLOTS 16
#define SLOTE (256 * KA)   // elements per ring slot

// workspace layout (bytes)
#define RING_OFF   0ull                       // fp16 16*256*1280 = 10,485,760 (aliases WfullT)
#define WFULLT_OFF 0ull                       // fp16 [4096][1536] = 12,582,912 (init-only)
#define WDT_OFF    12582912ull                // fp16 [256][1024]  = 524,288
#define XH_OFF     13107200ull                // fp16 [256][256][256] = 33,554,432
#define CNT_OFF    46661632ull                // sub-counters (1KB region)
#define WS_NEEDED  46663680ull

// counter layout (ints): hcnt grp0 @0..8, grp1 @64..72; ycnt grp0 @128..136, grp1 @192..200
#define HCNT(g) ((g) * 64)
#define YCNT(g) (128 + (g) * 64)

#define LDS_SLAB_BYTES 98304                  // 32 vcols * 192 kblks * 16B
#define LDS_WDT_BYTES  32768                  // 16 cols * 128 kblks * 16B
#define LDS_ZBUF_BYTES 16896                  // [128][33] f32
#define LDS_TOTAL (LDS_SLAB_BYTES + LDS_WDT_BYTES + LDS_ZBUF_BYTES)

#define AGENT  __HIP_MEMORY_SCOPE_AGENT

__device__ __forceinline__ float sigf(float x) {
    return 1.0f / (1.0f + __expf(-x));
}
__device__ __forceinline__ float tanhfast(float x) {
    return 1.0f - 2.0f / (__expf(2.0f * x) + 1.0f);
}

// ---- sub-counter barrier (one 64B line per group/type) ----
__device__ __forceinline__ void garrive(int* base, int j) {
    __syncthreads();   // vmcnt(0): all sc1 data stores retired at coherence point
    if (threadIdx.x == 0)
        __hip_atomic_fetch_add(base + j, 1, __ATOMIC_RELAXED, AGENT);
}
__device__ __forceinline__ void gwait(int* base, int target) {
    if (threadIdx.x < 8) {
        while (__hip_atomic_load(base + threadIdx.x, __ATOMIC_RELAXED, AGENT) < target)
            __builtin_amdgcn_s_sleep(2);
    }
    __syncthreads();
}
__device__ __forceinline__ void gwait_both(int* cnts, int target) {
    if (threadIdx.x < 8) {
        while (__hip_atomic_load(cnts + HCNT(0) + threadIdx.x, __ATOMIC_RELAXED, AGENT) < target ||
               __hip_atomic_load(cnts + HCNT(1) + threadIdx.x, __ATOMIC_RELAXED, AGENT) < target)
            __builtin_amdgcn_s_sleep(2);
    }
    __syncthreads();
}

// ---------------- prep kernels ----------------
__global__ void prep_w(const float* __restrict__ Wx, const float* __restrict__ Wh,
                       const float* __restrict__ Wd,
                       _Float16* __restrict__ WfullT, _Float16* __restrict__ WdT) {
    int bid = blockIdx.x;
    if (bid < 4096) {
        int n = bid;
        for (int k = threadIdx.x; k < KF; k += 256) {
            float v;
            if (k < 256)       v = Wx[(size_t)k * 4096 + n];
            else if (k < 1280) v = Wh[(size_t)(k - 256) * 4096 + n];
            else               v = Wx[(size_t)(k - 1024) * 4096 + n];
            WfullT[(size_t)n * KF + k] = (_Float16)v;
        }
    } else {
        int o = bid - 4096;
        for (int k = threadIdx.x; k < HID; k += 256) {
            WdT[(size_t)o * HID + k] = (_Float16)Wd[(size_t)k * OUTD + o];
        }
    }
}

__global__ void prep_x(const float* __restrict__ x, _Float16* __restrict__ xh, int* cnts) {
    size_t i0 = ((size_t)blockIdx.x * 256 + threadIdx.x) * 8;
    float4 a = *(const float4*)(x + i0);
    float4 c = *(const float4*)(x + i0 + 4);
    f16x8 v;
    v[0] = (_Float16)a.x; v[1] = (_Float16)a.y; v[2] = (_Float16)a.z; v[3] = (_Float16)a.w;
    v[4] = (_Float16)c.x; v[5] = (_Float16)c.y; v[6] = (_Float16)c.z; v[7] = (_Float16)c.w;
    *(f16x8*)(xh + i0) = v;
    if (blockIdx.x == 0) cnts[threadIdx.x] = 0;   // zero 1KB counter region
}

// ---------------- GEMM part: NS K-steps of 2 MFMAs, rotated traversal ----------------
// One M-tile (16 rows) per wave, 2 N-tiles (32 vcols). K-order starts at
// kk-offset `rot` (mod NS via MASK) so different blocks fill different
// panel chunks first. FP32 accumulate -> order only changes rounding.
template<int NS, int MASK, typename AL>
__device__ __forceinline__ void gemmPartR(AL&& aload, const _Float16* slab, int kbB,
                                          int rot, int rl, int kg, f32x4 (&acc)[2]) {
    constexpr int PFD = (NS < 16) ? NS : 16;
    f16x8 pa[PFD];
#pragma unroll
    for (int i = 0; i < PFD; ++i) pa[i] = aload((i + rot) & MASK);
    const int sw = rl & 7;
    const _Float16* bb0 = slab + (size_t)rl * 1536;
    const _Float16* bb1 = slab + (size_t)(16 + rl) * 1536;
#pragma unroll
    for (int kk = 0; kk < NS; ++kk) {
        int pos = (kk + rot) & MASK;
        int kblk = kbB + pos * 4 + kg;
        int idx = (kblk ^ sw) * 8;
        f16x8 b0 = *(const f16x8*)(bb0 + idx);
        f16x8 b1 = *(const f16x8*)(bb1 + idx);
        f16x8 a0 = pa[kk % PFD];
        if (kk + PFD < NS) pa[kk % PFD] = aload((kk + PFD + rot) & MASK);
        acc[0] = __builtin_amdgcn_mfma_f32_16x16x32_f16(a0, b0, acc[0], 0, 0, 0);
        acc[1] = __builtin_amdgcn_mfma_f32_16x16x32_f16(a0, b1, acc[1], 0, 0, 0);
    }
}

// ---------------- persistent LSTM ----------------
// 512 threads = 8 waves; phase A: wave w owns batch rows bat0 + w*16 .. +16.
// Epilogue + phase B: Round-7 code on tid<256 (4 waves), w<4 for phase-B MFMA.
__global__ __launch_bounds__(512, 2) void lstm_persist(
        const _Float16* __restrict__ WfullT, const _Float16* __restrict__ WdT,
        const _Float16* __restrict__ xh, const float* __restrict__ b,
        const float* __restrict__ bd,
        _Float16* __restrict__ ring,
        int* cnts, float* __restrict__ out) {
    extern __shared__ char dynsm[];
    _Float16* slab = (_Float16*)dynsm;                              // [32][192][8]
    _Float16* wdt  = (_Float16*)(dynsm + LDS_SLAB_BYTES);           // [16][128][8]
    float* zbuf = (float*)(dynsm + LDS_SLAB_BYTES + LDS_WDT_BYTES); // [128][33]

    const int tid = threadIdx.x, bid = blockIdx.x;
    const int w = tid >> 6, lane = tid & 63;
    const int rl = lane & 15, kg = lane >> 4;

    const int bat0 = (bid >> 7) << 7;
    const int n0 = (bid & 127) << 3;
    const int r0 = (bid >> 4) << 4;
    const int c0 = (bid & 15) << 4;
    const int gid = bid >> 7;
    const int subj = (bid >> 4) & 7;      // 16 blocks per sub-counter
    const int rotS = (bid >> 3) & 7;      // varies WITHIN an XCD (bid%8 = XCD)
    const int rotL = rotS * 4;            // chunk rotation for NS=32 (4 kk/chunk)

    int* hcnt = cnts + HCNT(gid);
    int* ycnt = cnts + YCNT(gid);

    // ---- init: weight slab + WdT tile (swizzled) into LDS ----
    for (int i = tid; i < 32 * 192; i += 512) {
        int vcol = i / 192, kblk = i % 192;
        int n = (vcol & 3) * 1024 + n0 + (vcol >> 2);
        f16x8 v = *(const f16x8*)(WfullT + (size_t)n * KF + kblk * 8);
        *(f16x8*)(slab + ((size_t)vcol * 192 + (kblk ^ (vcol & 7))) * 8) = v;
    }
    for (int i = tid; i < 16 * 128; i += 512) {
        int wcol = i >> 7, kb = i & 127;
        f16x8 v = *(const f16x8*)(WdT + (size_t)(c0 + wcol) * HID + kb * 8);
        *(f16x8*)(wdt + ((size_t)wcol * 128 + (kb ^ (wcol & 7))) * 8) = v;
    }
    // R7 epilogue mapping (tid<256 active)
    const int trow = tid >> 1;          // 0..127 for tid<256
    const int ccB = (tid & 1) * 4;      // 0 or 4
    float bb[4][4];
#pragma unroll
    for (int g = 0; g < 4; ++g)
#pragma unroll
        for (int c2 = 0; c2 < 4; ++c2)
            bb[g][c2] = b[g * 1024 + n0 + ((ccB + c2) & 7)];
    const float bdv = bd[c0 + (tid & 15)];
    float creg[4] = {0.f, 0.f, 0.f, 0.f};

    const size_t arow = (size_t)(bat0 + w * 16 + rl);

    // epilogue: acc(z) -> zbuf; R7 gate/c/h path on tid<256; h -> slotW (sc1)
    auto epilogue = [&](f32x4 (&A)[2], _Float16* slotW) {
#pragma unroll
        for (int nt = 0; nt < 2; ++nt)
#pragma unroll
            for (int r = 0; r < 4; ++r) {
                int zrow = w * 16 + kg * 4 + r;
                zbuf[zrow * 33 + nt * 16 + rl] = A[nt][r];
            }
        __syncthreads();
        if (tid < 256) {
            union { f16x4 v; unsigned long long u; } hu;
#pragma unroll
            for (int c2 = 0; c2 < 4; ++c2) {
                int cc = ccB + c2;
                float zi = zbuf[trow * 33 + cc * 4 + 0];
                float zf = zbuf[trow * 33 + cc * 4 + 1];
                float zg = zbuf[trow * 33 + cc * 4 + 2];
                float zo = zbuf[trow * 33 + cc * 4 + 3];
                float iv = sigf(zi + bb[0][c2]);
                float fv = sigf(zf + bb[1][c2]);
                float gv = tanhfast(zg + bb[2][c2]);
                float ov = sigf(zo + bb[3][c2]);
                float cnew = fv * creg[c2] + iv * gv;
                creg[c2] = cnew;
                hu.v[c2] = (_Float16)(ov * tanhfast(cnew));
            }
            __hip_atomic_store(
                (unsigned long long*)(slotW + (size_t)(bat0 + trow) * KA + n0 + ccB),
                hu.u, __ATOMIC_RELAXED, AGENT);
        }
    };

    // phase B (R7): waves 0-3 compute, K slice 256/wave; y -> out (NT) + slotT
    auto phaseB = [&](int t, _Float16* slotT, const f16x8* wa) {
        float* red = zbuf;
        if (w < 4) {
            const _Float16* hp = slotT + (size_t)(r0 + rl) * KA + (w << 8) + kg * 8;
            f16x8 ha[8];
#pragma unroll
            for (int it = 0; it < 8; ++it)
                ha[it] = *(const f16x8*)(hp + it * 32);
            f32x4 accB; accB[0] = 0.f; accB[1] = 0.f; accB[2] = 0.f; accB[3] = 0.f;
#pragma unroll
            for (int it = 0; it < 8; ++it)
                accB = __builtin_amdgcn_mfma_f32_16x16x32_f16(ha[it], wa[it], accB, 0, 0, 0);
#pragma unroll
            for (int r = 0; r < 4; ++r)
                red[w * 256 + (kg * 4 + r) * 16 + rl] = accB[r];
        }
        __syncthreads();
        unsigned short* ys = (unsigned short*)(zbuf + 1024);
        if (tid < 256) {
            int rr = tid >> 4, cc = tid & 15;
            float s = red[rr * 16 + cc] + red[256 + rr * 16 + cc] +
                      red[512 + rr * 16 + cc] + red[768 + rr * 16 + cc];
            float y = tanhfast(s + bdv);
            __builtin_nontemporal_store(
                y, out + (size_t)(r0 + rr) * 65536 + (size_t)t * 256 + (c0 + cc));
            union { _Float16 h; unsigned short u; } cv; cv.h = (_Float16)y;
            ys[tid] = cv.u;
        }
        __syncthreads();
        if (tid < 64) {
            unsigned long long yv = *(const unsigned long long*)(ys + tid * 4);
            int row = r0 + (tid >> 2), colb = c0 + (tid & 3) * 4;
            __hip_atomic_store(
                (unsigned long long*)(slotT + (size_t)row * KA + 1024 + colb),
                yv, __ATOMIC_RELAXED, AGENT);
        }
    };

    // ---- init barrier: all WfullT reads complete before ring overwrites it ----
    garrive(hcnt, subj);            // epoch 1 (target 16 per sub-counter)
    gwait_both(cnts, 16);

    // ---- t = 0: x-only GEMM (h=c=y=0), h_0 -> slot 0 ----
    f32x4 acc[2];
    acc[0][0] = 0.f; acc[0][1] = 0.f; acc[0][2] = 0.f; acc[0][3] = 0.f;
    acc[1][0] = 0.f; acc[1][1] = 0.f; acc[1][2] = 0.f; acc[1][3] = 0.f;
    {
        const _Float16* xb = xh + arow * 65536 + kg * 8;
        auto loadX = [&](int kk) -> f16x8 {
            return *(const f16x8*)(xb + kk * 32);
        };
        gemmPartR<8, 7>(loadX, slab, 0, rotS, rl, kg, acc);
    }
    epilogue(acc, ring);
    garrive(hcnt, subj);            // h_0 announced (epoch 2)

    // ---- pipelined steady loop ----
    for (int t = 0; t < TSTEPS; ++t) {
        // ring-wrap staleness fence (reuse distance = 16 slots)
        if ((t & 15) == 0)
            __builtin_amdgcn_fence(__ATOMIC_ACQUIRE, "agent");

        _Float16* slotT = ring + (size_t)(t & (RSLOTS - 1)) * SLOTE;

        acc[0][0] = 0.f; acc[0][1] = 0.f; acc[0][2] = 0.f; acc[0][3] = 0.f;
        acc[1][0] = 0.f; acc[1][1] = 0.f; acc[1][2] = 0.f; acc[1][3] = 0.f;

        if (t < TSTEPS - 1) {   // xGEMM(t+1) — hides h_t flag propagation
            const _Float16* xb = xh + arow * 65536 + (size_t)(t + 1) * 256 + kg * 8;
            auto loadX = [&](int kk) -> f16x8 {
                return *(const f16x8*)(xb + kk * 32);
            };
            gemmPartR<8, 7>(loadX, slab, 0, rotS, rl, kg, acc);
        }

        // preload phase-B Wd fragments from LDS (R7 indexing; used by w<4)
        f16x8 wa[8];
#pragma unroll
        for (int it = 0; it < 8; ++it) {
            int kb = ((w & 3) << 5) + it * 4 + kg;
            wa[it] = *(const f16x8*)(wdt + ((size_t)rl * 128 + (kb ^ (rl & 7))) * 8);
        }

        gwait(hcnt, (t + 2) * 16);          // h_t visible group-wide
        phaseB(t, slotT, wa);               // y_t -> out + ring

        if (t < TSTEPS - 1) {
            garrive(ycnt, subj);            // y_t announced (epoch t+1)

            {   // hGEMM(t+1) reading h_t — rotated K so same-XCD blocks
                // fill different 128-col chunks of the panel in parallel
                const _Float16* hb = slotT + arow * KA + kg * 8;
                auto loadH = [&](int kk) -> f16x8 {
                    return *(const f16x8*)(hb + kk * 32);
                };
                gemmPartR<32, 31>(loadH, slab, 32, rotL, rl, kg, acc);
            }

            gwait(ycnt, (t + 1) * 16);      // y_t visible group-wide

            {   // yGEMM(t+1), rotated
                const _Float16* yb = slotT + arow * KA + 1024 + kg * 8;
                auto loadY = [&](int kk) -> f16x8 {
                    return *(const f16x8*)(yb + kk * 32);
                };
                gemmPartR<8, 7>(loadY, slab, 160, rotS, rl, kg, acc);
            }

            epilogue(acc, ring + (size_t)((t + 1) & (RSLOTS - 1)) * SLOTE);
            garrive(hcnt, subj);            // h_{t+1} announced (epoch t+3)
        }
    }
}

extern "C" void kernel_launch(void* const* d_in, const int* in_sizes, int n_in,
                              void* d_out, int out_size, void* d_ws, size_t ws_size,
                              hipStream_t stream) {
    const float* x  = (const float*)d_in[0];
    const float* Wx = (const float*)d_in[1];
    const float* Wh = (const float*)d_in[2];
    const float* b  = (const float*)d_in[3];
    const float* Wd = (const float*)d_in[4];
    const float* bd = (const float*)d_in[5];
    float* out = (float*)d_out;
    char* ws = (char*)d_ws;
    if (ws_size < WS_NEEDED) return;

    _Float16* WfullT = (_Float16*)(ws + WFULLT_OFF);
    _Float16* WdT    = (_Float16*)(ws + WDT_OFF);
    _Float16* xh     = (_Float16*)(ws + XH_OFF);
    _Float16* ring   = (_Float16*)(ws + RING_OFF);
    int*      cnts   = (int*)(ws + CNT_OFF);

    static int lds_set = 0;
    if (!lds_set) {
        hipFuncSetAttribute((const void*)lstm_persist,
                            hipFuncAttributeMaxDynamicSharedMemorySize, LDS_TOTAL);
        lds_set = 1;
    }

    prep_w<<<4352, 256, 0, stream>>>(Wx, Wh, Wd, WfullT, WdT);
    prep_x<<<8192, 256, 0, stream>>>(x, xh, cnts);
    lstm_persist<<<NBLK, 512, LDS_TOTAL, stream>>>(WfullT, WdT, xh, b, bd, ring, cnts, out);
}